// Round 25
// baseline (134.293 us; speedup 1.0000x reference)
//
#include <hip/hip_runtime.h>
#include <math.h>

#define NB   4
#define IH   128
#define IW   128
#define NTOK 16384        // IH*IW
#define CC   96
#define HID  192
#define QKD  48
#define EPSF 1e-5f
#define INV_N (1.0f/16384.0f)

typedef __attribute__((ext_vector_type(8))) short sh8;    // 8 bf16 (4 VGPRs)
typedef __attribute__((ext_vector_type(4))) short ush4;   // 4 bf16 (2 VGPRs)
typedef __attribute__((ext_vector_type(4))) float f32x4;  // 4 fp32

__device__ __forceinline__ float wave_sum64(float v){
    #pragma unroll
    for (int off = 32; off > 0; off >>= 1) v += __shfl_xor(v, off, 64);
    return v;
}
__device__ __forceinline__ float siluf(float x){ return x / (1.0f + __expf(-x)); }
__device__ __forceinline__ float geluf(float x){ return 0.5f*x*(1.0f + erff(x*0.7071067811865475f)); }

__device__ __forceinline__ unsigned short f2bf(float f){   // RNE float->bf16 bits
    union { float f; unsigned u; } x; x.f = f;
    unsigned u = x.u + 0x7FFFu + ((x.u >> 16) & 1u);
    return (unsigned short)(u >> 16);
}
__device__ __forceinline__ float b2f(unsigned hi16){       // bf16 bits (already <<16) -> f32
    union { unsigned u; float f; } c; c.u = hi16; return c.f;
}
__device__ __forceinline__ unsigned cvtpk(float a, float b){
    unsigned r;
    asm("v_cvt_pk_bf16_f32 %0, %1, %2" : "=v"(r) : "v"(a), "v"(b));
    return r;
}
__device__ __forceinline__ void swap32(unsigned &x, unsigned &y){
    asm volatile("v_permlane32_swap_b32 %0, %1" : "+v"(x), "+v"(y));
}
__device__ __forceinline__ void swap16(unsigned &x, unsigned &y){
    asm volatile("v_permlane16_swap_b32 %0, %1" : "+v"(x), "+v"(y));
}

// ---------------- 1. LayerNorm -> bf16 (8 rows/block, 16B nxim stores) ∥ conv-weight cvt ----------------
// blocks [0,8192): LN (512 thr, 8 waves x 1 row); [8192,8552): weight cvt (512 thr)
__global__ __launch_bounds__(512) void k_ln(const float* __restrict__ x,
                                            const float* __restrict__ w,
                                            const float* __restrict__ bb,
                                            unsigned short* __restrict__ nxbf,
                                            unsigned short* __restrict__ nxim,
                                            const float* __restrict__ s1, unsigned short* __restrict__ d1, int n1,
                                            const float* __restrict__ s2, unsigned short* __restrict__ d2, int n2){
    int bid = blockIdx.x;
    int tid = threadIdx.x;
    if (bid >= 8192){
        int i4 = ((bid - 8192)*512 + tid)*4;
        if (i4 < n1){
            float4 v = *(const float4*)(s1 + i4);
            unsigned u0 = cvtpk(v.x, v.y), u1 = cvtpk(v.z, v.w);
            ush4 o = {(short)u0, (short)(u0>>16), (short)u1, (short)(u1>>16)};
            *(ush4*)(d1 + i4) = o;
        } else {
            int j = i4 - n1;
            if (j < n2){
                float4 v = *(const float4*)(s2 + j);
                unsigned u0 = cvtpk(v.x, v.y), u1 = cvtpk(v.z, v.w);
                ush4 o = {(short)u0, (short)(u0>>16), (short)u1, (short)(u1>>16)};
                *(ush4*)(d2 + j) = o;
            }
        }
        return;
    }
    __shared__ unsigned short tile[8][96];
    int r = tid >> 6;                    // wave id = local row
    int row = bid*8 + r;
    int l = tid & 63;
    const float* xr = x + (size_t)row*CC;
    float a = xr[l];
    float b = (l < 32) ? xr[64+l] : 0.0f;
    float s = wave_sum64(a + b);
    float m = s * (1.0f/96.0f);
    float d1f = a - m;
    float d2f = b - m;
    float sq = d1f*d1f + ((l < 32) ? d2f*d2f : 0.0f);
    float var = wave_sum64(sq) * (1.0f/96.0f);
    float rstd = rsqrtf(var + EPSF);
    unsigned short b1 = f2bf(d1f*rstd*w[l] + bb[l]);
    nxbf[(size_t)row*CC + l] = b1;
    tile[r][l] = b1;
    if (l < 32){
        unsigned short b2 = f2bf(d2f*rstd*w[64+l] + bb[64+l]);
        nxbf[(size_t)row*CC + 64 + l] = b2;
        tile[r][64+l] = b2;
    }
    __syncthreads();
    if (tid < 96){
        int row0 = bid*8;
        int bb2 = row0 >> 14, hw = row0 & 16383;
        sh8 v = {(short)tile[0][tid], (short)tile[1][tid], (short)tile[2][tid], (short)tile[3][tid],
                 (short)tile[4][tid], (short)tile[5][tid], (short)tile[6][tid], (short)tile[7][tid]};
        *(sh8*)(nxim + (((size_t)(bb2*96 + tid)) << 14) + hw) = v;
    }
}

// ---------------- conv body (patch GEMM, SPLITK=384 = 6 chunks of 64) ----------------
__device__ __forceinline__ void conv_body(const unsigned short* __restrict__ nxim,
                                          const unsigned short* __restrict__ wbf,
                                          float* __restrict__ part,
                                          int posLog, int pdimLog, int pszLog,
                                          int kTotal, int rb, int split,
                                          unsigned short* pt, unsigned short* wt){
    const int NCH = 6;
    int tid = threadIdx.x;
    int lane = tid & 63, wid = tid >> 6, lo = lane & 15, g = lane >> 4;
    int psz = 1 << pszLog, pdim = 1 << pdimLog;
    int ksLog = 2*pszLog;
    int kb0 = split * 384;
    int cinc = (64 >> ksLog) << 14;

    int j   = tid & 15;
    int coff = (j*4) >> ksLog;
    int s   = (j*4) & (psz*psz - 1);
    int sy  = s >> pszLog, sx = s & (psz-1);
    int pAddr[4], pOff[4];
    #pragma unroll
    for (int i = 0; i < 4; i++){
        int p = (tid >> 4) + 16*i;
        int R = rb*64 + p;
        int b = R >> posLog, pp = R & ((1 << posLog) - 1);
        int pi = pp >> pdimLog, pj = pp & (pdim-1);
        pAddr[i] = (((b*96 + coff) + (kb0 >> ksLog)) << 14) + (pi*psz + sy)*IW + pj*psz + sx;
        pOff[i]  = p*72 + j*4;
    }
    int jj = tid & 7;
    int wAddr[3], wOff[3];
    #pragma unroll
    for (int i = 0; i < 3; i++){
        int o = (tid >> 3) + 32*i;
        wAddr[i] = o*kTotal + kb0 + jj*8;
        wOff[i]  = o*72 + jj*8;
    }

    f32x4 acc[6];
    #pragma unroll
    for (int ct = 0; ct < 6; ct++) acc[ct] = (f32x4){0.f,0.f,0.f,0.f};

    ush4 pr[4]; sh8 wr[3];
    #pragma unroll
    for (int i = 0; i < 4; i++) pr[i] = *(const ush4*)(nxim + pAddr[i]);
    #pragma unroll
    for (int i = 0; i < 3; i++) wr[i] = *(const sh8*)(wbf + wAddr[i]);

    for (int ch = 0; ch < NCH; ch++){
        __syncthreads();
        #pragma unroll
        for (int i = 0; i < 4; i++) *(ush4*)&pt[pOff[i]] = pr[i];
        #pragma unroll
        for (int i = 0; i < 3; i++) *(sh8*)&wt[wOff[i]] = wr[i];
        if (ch < NCH-1){
            #pragma unroll
            for (int i = 0; i < 4; i++){ pAddr[i] += cinc; pr[i] = *(const ush4*)(nxim + pAddr[i]); }
            #pragma unroll
            for (int i = 0; i < 3; i++){ wAddr[i] += 64;  wr[i] = *(const sh8*)(wbf + wAddr[i]); }
        }
        __syncthreads();

        sh8 a0 = *(const sh8*)&pt[(wid*16 + lo)*72 + g*8];
        sh8 a1 = *(const sh8*)&pt[(wid*16 + lo)*72 + 32 + g*8];
        #pragma unroll
        for (int ct = 0; ct < 6; ct++){
            sh8 b0 = *(const sh8*)&wt[(ct*16 + lo)*72 + g*8];
            sh8 b1 = *(const sh8*)&wt[(ct*16 + lo)*72 + 32 + g*8];
            acc[ct] = __builtin_amdgcn_mfma_f32_16x16x32_bf16(a0, b0, acc[ct], 0, 0, 0);
            acc[ct] = __builtin_amdgcn_mfma_f32_16x16x32_bf16(a1, b1, acc[ct], 0, 0, 0);
        }
    }

    int rowsTotal = NB << posLog;
    #pragma unroll
    for (int ct = 0; ct < 6; ct++){
        int o = ct*16 + lo;
        #pragma unroll
        for (int jx = 0; jx < 4; jx++){
            int R = rb*64 + wid*16 + g*4 + jx;
            part[((size_t)split*rowsTotal + R)*96 + o] = acc[ct][jx];
        }
    }
}

// ---------------- 2. merged mid kernel: conv1 ∥ conv2 ∥ hgemm ----------------
__global__ __launch_bounds__(256) void k_mid(const unsigned short* __restrict__ nxbf,
                                             const unsigned short* __restrict__ nxim,
                                             const float* __restrict__ Wh,
                                             const float* __restrict__ bh,
                                             const unsigned short* __restrict__ w1bf,
                                             const unsigned short* __restrict__ w2bf,
                                             unsigned short* __restrict__ vbuf,
                                             unsigned short* __restrict__ gate,
                                             float* __restrict__ part1,
                                             float* __restrict__ part2){
    __shared__ unsigned short smem[192*100];
    int bid = blockIdx.x;
    if (bid < 512){
        unsigned short* pt = smem;
        unsigned short* wt = smem + 64*72;
        if (bid < 256) conv_body(nxim, w1bf, part1, 8, 4, 3, 6144, bid & 15, bid >> 4, pt, wt);
        else { int b2 = bid - 256; conv_body(nxim, w2bf, part2, 10, 5, 2, 1536, b2 & 63, b2 >> 6, pt, wt); }
        return;
    }
    // ---- hgemm ----
    unsigned short* whbf = smem;               // [col][k] stride 100
    int tid  = threadIdx.x;
    int lane = tid & 63;
    int wid  = tid >> 6;
    int lo   = lane & 15;
    int g    = lane >> 4;
    int row0 = (bid - 512)*64 + wid*16;

    #pragma unroll
    for (int it = 0; it < 36; it++){
        int pidx = tid + it*256;
        int k = pidx / 96, cp = (pidx - k*96)*2;
        float2 v = *(const float2*)&Wh[k*HID + cp];
        unsigned u = cvtpk(v.x, v.y);
        whbf[cp*100 + k]     = (unsigned short)u;
        whbf[(cp+1)*100 + k] = (unsigned short)(u >> 16);
    }

    sh8 a[3];
    {
        const unsigned short* ar = nxbf + (size_t)(row0 + lo)*CC;
        #pragma unroll
        for (int kc = 0; kc < 3; kc++)
            a[kc] = *(const sh8*)(ar + kc*32 + g*8);
    }
    __syncthreads();

    f32x4 acc[12];
    #pragma unroll
    for (int ct = 0; ct < 12; ct++) acc[ct] = (f32x4){0.f,0.f,0.f,0.f};
    #pragma unroll
    for (int ct = 0; ct < 12; ct++){
        #pragma unroll
        for (int kc = 0; kc < 3; kc++){
            sh8 bw = *(const sh8*)&whbf[(ct*16 + lo)*100 + kc*32 + g*8];
            acc[ct] = __builtin_amdgcn_mfma_f32_16x16x32_bf16(a[kc], bw, acc[ct], 0, 0, 0);
        }
    }

    #pragma unroll
    for (int ct = 0; ct < 12; ct++){
        int col = ct*16 + lo;
        float bcol = bh[col];
        #pragma unroll
        for (int j = 0; j < 4; j++){
            size_t row = row0 + g*4 + j;
            float hv = siluf(acc[ct][j] + bcol);
            unsigned short hb = (unsigned short)cvtpk(hv, hv);
            if (col < 96) vbuf[row*CC + col] = hb;
            else          gate[row*CC + col - 96] = hb;
        }
    }
}

// ---------------- 4. merged reduce: 4 rows/block, 1 wave per row, no barriers ----------------
__global__ __launch_bounds__(256) void k_reduce(const float* __restrict__ part1,
                                                const float* __restrict__ part2,
                                                const float* __restrict__ cb1, const float* __restrict__ cb2,
                                                const float* __restrict__ lw1, const float* __restrict__ lw2,
                                                const float* __restrict__ lb1, const float* __restrict__ lb2,
                                                const float* __restrict__ wqk,
                                                const float* __restrict__ bqk,
                                                const float* __restrict__ g1, const float* __restrict__ g2,
                                                const float* __restrict__ be1, const float* __restrict__ be2,
                                                unsigned short* __restrict__ qp1, unsigned short* __restrict__ qp2,
                                                unsigned short* __restrict__ kt1, unsigned short* __restrict__ kt2){
    __shared__ float xsh[4][96];
    int wv  = threadIdx.x >> 6;
    int id  = blockIdx.x*4 + wv;         // merged row id (0..5119)
    bool fst = id < 1024;
    int row   = fst ? id : id - 1024;
    int nsplit= fst ? 16 : 4;
    int rows  = fst ? 1024 : 4096;
    int Mper  = fst ? 256 : 1024;
    const float* part = fst ? part1 : part2;
    const float* cbias= fst ? cb1 : cb2;
    const float* lw   = fst ? lw1 : lw2;
    const float* lb   = fst ? lb1 : lb2;
    const float* g    = fst ? g1 : g2;
    const float* be   = fst ? be1 : be2;
    unsigned short* qp = fst ? qp1 : qp2;
    unsigned short* ktp= fst ? kt1 : kt2;

    int l = threadIdx.x & 63;
    float y1 = 0.0f, y2 = 0.0f;
    for (int s = 0; s < nsplit; s++){
        const float* pr = part + ((size_t)s*rows + row)*96;
        y1 += pr[l];
        if (l < 32) y2 += pr[64+l];
    }
    y1 += cbias[l];
    if (l < 32) y2 += cbias[64+l];
    float s = wave_sum64(y1 + ((l < 32) ? y2 : 0.0f));
    float m = s * (1.0f/96.0f);
    float d1 = y1 - m, d2 = y2 - m;
    float var = wave_sum64(d1*d1 + ((l < 32) ? d2*d2 : 0.0f)) * (1.0f/96.0f);
    float rstd = rsqrtf(var + EPSF);
    xsh[wv][l] = geluf(d1*rstd*lw[l] + lb[l]);
    if (l < 32) xsh[wv][64+l] = geluf(d2*rstd*lw[64+l] + lb[64+l]);
    // same-wave LDS write->read: ordered by lgkmcnt, no barrier needed
    if (l < 48){
        float z = bqk[l];
        #pragma unroll 4
        for (int c = 0; c < 96; c++) z += xsh[wv][c]*wqk[c*48 + l];
        z = siluf(z);
        float qv = (z*g[l]    + be[l]) * INV_N;   // fold 1/N into q
        float kv =  z*g[48+l] + be[48+l];
        int b = row / Mper, p = row - b*Mper;
        qp[(size_t)row*64 + l] = f2bf(qv);
        ktp[((size_t)b*48 + l)*Mper + p] = f2bf(kv);
    } else {
        qp[(size_t)row*64 + l] = 0;      // zero the d-pad
    }
}

// ---------------- 5. fused attention(+final): 512 blocks x 128 rows (4 waves x 32, nt=2) ----------------
// q A-frags read DIRECT from global (L2-resident, per-lane 16B); only k staged in LDS.
__global__ __launch_bounds__(256) void k_attn(const unsigned short* __restrict__ vbuf,
                                              const unsigned short* __restrict__ gate,
                                              const unsigned short* __restrict__ qp1,
                                              const unsigned short* __restrict__ ktp1,
                                              const unsigned short* __restrict__ qp2,
                                              const unsigned short* __restrict__ ktp2,
                                              const float* __restrict__ projw,
                                              const float* __restrict__ projb,
                                              float* __restrict__ out){
    __shared__ unsigned short vt1s[4][32*56];   // V1 per wave [32 rows][48 cols] stride 56
    __shared__ unsigned short uni[16896];       // ks dbuf (6912) | vt2 (7168) + pjbf (9600)

    int blk  = blockIdx.x;               // 512 blocks x 128 rows
    int tid  = threadIdx.x;
    int wid  = tid >> 6;
    int lane = tid & 63;
    int lo   = lane & 15;
    int g    = lane >> 4;
    int row0 = blk*128 + wid*32;
    int bb   = (blk*128) >> 14;          // batch (uniform per block)

    unsigned short* vt1 = &vt1s[wid][0];
    unsigned short* vt2 = uni + wid*1792;                  // epilogue alias [32][56]
    unsigned short* pjbf = uni + 7168;                     // epilogue alias [96][100]

    int kd_ = tid >> 3, km_ = tid & 7;
    bool k2 = tid < 128;

    for (int kind = 0; kind < 2; kind++){
        int M = kind ? 1024 : 256;
        const unsigned short* qp = (kind ? qp2 : qp1) + (size_t)bb*M*64;
        const unsigned short* kt = (kind ? ktp2 : ktp1) + (size_t)bb*48*M;
        int voff = kind ? 48 : 0;

        sh8 vb[2][2];
        #pragma unroll
        for (int nt = 0; nt < 2; nt++){
            const unsigned short* vrow = vbuf + (size_t)(row0 + nt*16 + lo)*CC + voff;
            vb[nt][0] = *(const sh8*)(vrow + g*8);
            if (g < 2) vb[nt][1] = *(const sh8*)(vrow + 32 + g*8);
            else { sh8 z = {0,0,0,0,0,0,0,0}; vb[nt][1] = z; }
        }

        f32x4 acc[2][3];
        #pragma unroll
        for (int nt = 0; nt < 2; nt++)
            #pragma unroll
            for (int dt = 0; dt < 3; dt++) acc[nt][dt] = (f32x4){0.f,0.f,0.f,0.f};

        int nchunk = M >> 6;
        sh8 kr0 = *(const sh8*)(kt + (size_t)kd_*M + km_*8);
        sh8 kr1;
        if (k2) kr1 = *(const sh8*)(kt + (size_t)(32 + kd_)*M + km_*8);

        for (int ch = 0; ch < nchunk; ch++){
            int mb = ch*64;
            int bs = ch & 1;
            unsigned short* kb = uni + bs*3456;            // [48*72]
            *(sh8*)&kb[kd_*72 + km_*8] = kr0;
            if (k2) *(sh8*)&kb[(32 + kd_)*72 + km_*8] = kr1;
            __syncthreads();
            if (ch + 1 < nchunk){
                int mb2 = mb + 64;
                kr0 = *(const sh8*)(kt + (size_t)kd_*M + mb2 + km_*8);
                if (k2) kr1 = *(const sh8*)(kt + (size_t)(32 + kd_)*M + mb2 + km_*8);
            }

            // gemm1 (swapped): q A-frags direct from global (per-lane, L2); q pre-scaled by 1/N
            f32x4 c[4][2];
            #pragma unroll
            for (int mt = 0; mt < 4; mt++){
                const unsigned short* qrow = qp + (size_t)(mb + mt*16 + lo)*64;
                sh8 aq0 = *(const sh8*)(qrow + g*8);
                sh8 aq1 = *(const sh8*)(qrow + 32 + g*8);
                #pragma unroll
                for (int nt = 0; nt < 2; nt++){
                    f32x4 cc = (f32x4){0.f,0.f,0.f,0.f};
                    cc = __builtin_amdgcn_mfma_f32_16x16x32_bf16(aq0, vb[nt][0], cc, 0,0,0);
                    cc = __builtin_amdgcn_mfma_f32_16x16x32_bf16(aq1, vb[nt][1], cc, 0,0,0);
                    c[mt][nt] = cc;
                }
            }

            sh8 pa0[2], pa1[2];
            #pragma unroll
            for (int nt = 0; nt < 2; nt++){
                #pragma unroll
                for (int h = 0; h < 2; h++){
                    f32x4 cm0 = c[h*2][nt];
                    f32x4 cm1 = c[h*2+1][nt];
                    float p00 = fmaxf(cm0[0], 0.f); p00 *= p00;
                    float p01 = fmaxf(cm0[1], 0.f); p01 *= p01;
                    float p02 = fmaxf(cm0[2], 0.f); p02 *= p02;
                    float p03 = fmaxf(cm0[3], 0.f); p03 *= p03;
                    float p10 = fmaxf(cm1[0], 0.f); p10 *= p10;
                    float p11 = fmaxf(cm1[1], 0.f); p11 *= p11;
                    float p12 = fmaxf(cm1[2], 0.f); p12 *= p12;
                    float p13 = fmaxf(cm1[3], 0.f); p13 *= p13;
                    unsigned a0 = cvtpk(p00, p01);
                    unsigned a1 = cvtpk(p02, p03);
                    unsigned b0 = cvtpk(p10, p11);
                    unsigned b1 = cvtpk(p12, p13);
                    swap32(a0, b0); swap16(a0, b0);
                    swap32(a1, b1); swap16(a1, b1);
                    union { unsigned u[4]; sh8 v; } pk;
                    pk.u[0] = a0; pk.u[1] = a1; pk.u[2] = b0; pk.u[3] = b1;
                    if (h == 0) pa0[nt] = pk.v; else pa1[nt] = pk.v;
                }
            }

            #pragma unroll
            for (int dt = 0; dt < 3; dt++){
                sh8 bk0 = *(const sh8*)&kb[(dt*16 + lo)*72 + g*8];
                sh8 bk1 = *(const sh8*)&kb[(dt*16 + lo)*72 + 32 + g*8];
                #pragma unroll
                for (int nt = 0; nt < 2; nt++){
                    acc[nt][dt] = __builtin_amdgcn_mfma_f32_16x16x32_bf16(pa0[nt], bk0, acc[nt][dt], 0, 0, 0);
                    acc[nt][dt] = __builtin_amdgcn_mfma_f32_16x16x32_bf16(pa1[nt], bk1, acc[nt][dt], 0, 0, 0);
                }
            }
        }

        if (kind == 0){
            #pragma unroll
            for (int nt = 0; nt < 2; nt++)
                #pragma unroll
                for (int dt = 0; dt < 3; dt++)
                    #pragma unroll
                    for (int j = 0; j < 4; j++)
                        vt1[(nt*16 + g*4 + j)*56 + dt*16 + lo] =
                            (unsigned short)cvtpk(acc[nt][dt][j], acc[nt][dt][j]);
        } else {
            __syncthreads();             // all waves done with ks before vt2/pjbf overwrite
            #pragma unroll
            for (int nt = 0; nt < 2; nt++)
                #pragma unroll
                for (int dt = 0; dt < 3; dt++)
                    #pragma unroll
                    for (int j = 0; j < 4; j++)
                        vt2[(nt*16 + g*4 + j)*56 + dt*16 + lo] =
                            (unsigned short)cvtpk(acc[nt][dt][j], acc[nt][dt][j]);
        }
    }

    #pragma unroll
    for (int it = 0; it < 18; it++){
        int pidx = tid + it*256;
        int k = pidx / 48, cp = (pidx - k*48)*2;
        float2 v = *(const float2*)&projw[k*CC + cp];
        unsigned u = cvtpk(v.x, v.y);
        pjbf[cp*100 + k]     = (unsigned short)u;
        pjbf[(cp+1)*100 + k] = (unsigned short)(u >> 16);
    }
    __syncthreads();

    #pragma unroll
    for (int ntp = 0; ntp < 2; ntp++){
        int rl = ntp*16 + lo;
        size_t grow = row0 + rl;
        sh8 a[3];
        #pragma unroll
        for (int kc = 0; kc < 3; kc++){
            int d0 = kc*32 + g*8;
            const unsigned short* xsrc = (d0 < 48) ? &vt1[rl*56 + d0] : &vt2[rl*56 + d0 - 48];
            union { sh8 v; unsigned u[4]; } xu, gu, pk;
            xu.v = *(const sh8*)xsrc;
            gu.v = *(const sh8*)(gate + grow*CC + d0);
            #pragma unroll
            for (int i = 0; i < 4; i++){
                float xl = b2f(xu.u[i] << 16), xh = b2f(xu.u[i] & 0xffff0000u);
                float gl = b2f(gu.u[i] << 16), gh = b2f(gu.u[i] & 0xffff0000u);
                pk.u[i] = cvtpk(xl*gl, xh*gh);
            }
            a[kc] = pk.v;
        }

        f32x4 pacc[6];
        #pragma unroll
        for (int ct = 0; ct < 6; ct++) pacc[ct] = (f32x4){0.f,0.f,0.f,0.f};
        #pragma unroll
        for (int ct = 0; ct < 6; ct++){
            #pragma unroll
            for (int kc = 0; kc < 3; kc++){
                sh8 bw = *(const sh8*)&pjbf[(ct*16 + lo)*100 + kc*32 + g*8];
                pacc[ct] = __builtin_amdgcn_mfma_f32_16x16x32_bf16(a[kc], bw, pacc[ct], 0, 0, 0);
            }
        }

        #pragma unroll
        for (int ct = 0; ct < 6; ct++){
            int col = ct*16 + lo;
            float bcol = projb[col];
            #pragma unroll
            for (int j = 0; j < 4; j++){
                int rl2 = ntp*16 + g*4 + j;
                unsigned short xb = (col < 48) ? vt1[rl2*56 + col] : vt2[rl2*56 + col - 48];
                out[(size_t)(row0 + rl2)*CC + col] = pacc[ct][j] + bcol + b2f((unsigned)xb << 16);
            }
        }
    }
}

extern "C" void kernel_launch(void* const* d_in, const int* in_sizes, int n_in,
                              void* d_out, int out_size, void* d_ws, size_t ws_size,
                              hipStream_t stream){
    const float* x      = (const float*)d_in[0];
    const float* norm_w = (const float*)d_in[3];
    const float* norm_b = (const float*)d_in[4];
    const float* Wh     = (const float*)d_in[5];
    const float* bh     = (const float*)d_in[6];
    const float* Wqk    = (const float*)d_in[7];
    const float* bqk    = (const float*)d_in[8];
    const float* g1     = (const float*)d_in[9];
    const float* be1    = (const float*)d_in[10];
    const float* g2     = (const float*)d_in[11];
    const float* be2    = (const float*)d_in[12];
    const float* sr1_w  = (const float*)d_in[13];
    const float* sr1_b  = (const float*)d_in[14];
    const float* sr2_w  = (const float*)d_in[15];
    const float* sr2_b  = (const float*)d_in[16];
    const float* n1_w   = (const float*)d_in[17];
    const float* n1_b   = (const float*)d_in[18];
    const float* n2_w   = (const float*)d_in[19];
    const float* n2_b   = (const float*)d_in[20];
    const float* proj_w = (const float*)d_in[21];
    const float* proj_b = (const float*)d_in[22];
    float* out = (float*)d_out;

    float* ws = (float*)d_ws;
    size_t off = 0;
    unsigned short* nxbf = (unsigned short*)(ws + off); off += (size_t)NB*NTOK*CC/2;
    unsigned short* nxim = (unsigned short*)(ws + off); off += (size_t)NB*NTOK*CC/2;
    unsigned short* w1bf = (unsigned short*)(ws + off); off += (size_t)96*6144/2;
    unsigned short* w2bf = (unsigned short*)(ws + off); off += (size_t)96*1536/2;
    unsigned short* vbuf = (unsigned short*)(ws + off); off += (size_t)NB*NTOK*CC/2;
    unsigned short* gate = (unsigned short*)(ws + off); off += (size_t)NB*NTOK*CC/2;
    unsigned short* qp1 = (unsigned short*)(ws + off); off += (size_t)NB*256*64/2;
    unsigned short* kt1 = (unsigned short*)(ws + off); off += (size_t)NB*48*256/2;
    unsigned short* qp2 = (unsigned short*)(ws + off); off += (size_t)NB*1024*64/2;
    unsigned short* kt2 = (unsigned short*)(ws + off); off += (size_t)NB*48*1024/2;
    float* part1= ws + off; off += (size_t)16*NB*256*96;
    float* part2= ws + off; off += (size_t)4*NB*1024*96;
    if (ws_size < off*sizeof(float)) return;

    k_ln   <<<8552, 512, 0, stream>>>(x, norm_w, norm_b, nxbf, nxim,
                                      sr1_w, w1bf, 96*6144, sr2_w, w2bf, 96*1536);
    k_mid  <<<1536, 256, 0, stream>>>(nxbf, nxim, Wh, bh, w1bf, w2bf, vbuf, gate, part1, part2);
    k_reduce<<<1280, 256, 0, stream>>>(part1, part2, sr1_b, sr2_b, n1_w, n2_w, n1_b, n2_b,
                                       Wqk, bqk, g1, g2, be1, be2, qp1, qp2, kt1, kt2);
    k_attn <<<512, 256, 0, stream>>>(vbuf, gate, qp1, kt1, qp2, kt2, proj_w, proj_b, out);
}

// Round 26
// 109.162 us; speedup vs baseline: 1.2302x; 1.2302x over previous
//
#include <hip/hip_runtime.h>
#include <math.h>

#define NB   4
#define IH   128
#define IW   128
#define NTOK 16384        // IH*IW
#define CC   96
#define HID  192
#define QKD  48
#define EPSF 1e-5f
#define INV_N (1.0f/16384.0f)

typedef __attribute__((ext_vector_type(8))) short sh8;    // 8 bf16 (4 VGPRs)
typedef __attribute__((ext_vector_type(4))) short ush4;   // 4 bf16 (2 VGPRs)
typedef __attribute__((ext_vector_type(4))) float f32x4;  // 4 fp32

__device__ __forceinline__ float wave_sum64(float v){
    #pragma unroll
    for (int off = 32; off > 0; off >>= 1) v += __shfl_xor(v, off, 64);
    return v;
}
__device__ __forceinline__ float siluf(float x){ return x / (1.0f + __expf(-x)); }
__device__ __forceinline__ float geluf(float x){ return 0.5f*x*(1.0f + erff(x*0.7071067811865475f)); }

__device__ __forceinline__ unsigned short f2bf(float f){   // RNE float->bf16 bits
    union { float f; unsigned u; } x; x.f = f;
    unsigned u = x.u + 0x7FFFu + ((x.u >> 16) & 1u);
    return (unsigned short)(u >> 16);
}
__device__ __forceinline__ float b2f(unsigned hi16){       // bf16 bits (already <<16) -> f32
    union { unsigned u; float f; } c; c.u = hi16; return c.f;
}
__device__ __forceinline__ unsigned cvtpk(float a, float b){
    unsigned r;
    asm("v_cvt_pk_bf16_f32 %0, %1, %2" : "=v"(r) : "v"(a), "v"(b));
    return r;
}
__device__ __forceinline__ void swap32(unsigned &x, unsigned &y){
    asm volatile("v_permlane32_swap_b32 %0, %1" : "+v"(x), "+v"(y));
}
__device__ __forceinline__ void swap16(unsigned &x, unsigned &y){
    asm volatile("v_permlane16_swap_b32 %0, %1" : "+v"(x), "+v"(y));
}

// ---------------- 1. LayerNorm -> bf16 (8 rows/block, 16B nxim stores) ∥ conv-weight cvt ----------------
// blocks [0,8192): LN (512 thr, 8 waves x 1 row); [8192,8552): weight cvt (512 thr)
__global__ __launch_bounds__(512) void k_ln(const float* __restrict__ x,
                                            const float* __restrict__ w,
                                            const float* __restrict__ bb,
                                            unsigned short* __restrict__ nxbf,
                                            unsigned short* __restrict__ nxim,
                                            const float* __restrict__ s1, unsigned short* __restrict__ d1, int n1,
                                            const float* __restrict__ s2, unsigned short* __restrict__ d2, int n2){
    int bid = blockIdx.x;
    int tid = threadIdx.x;
    if (bid >= 8192){
        int i4 = ((bid - 8192)*512 + tid)*4;
        if (i4 < n1){
            float4 v = *(const float4*)(s1 + i4);
            unsigned u0 = cvtpk(v.x, v.y), u1 = cvtpk(v.z, v.w);
            ush4 o = {(short)u0, (short)(u0>>16), (short)u1, (short)(u1>>16)};
            *(ush4*)(d1 + i4) = o;
        } else {
            int j = i4 - n1;
            if (j < n2){
                float4 v = *(const float4*)(s2 + j);
                unsigned u0 = cvtpk(v.x, v.y), u1 = cvtpk(v.z, v.w);
                ush4 o = {(short)u0, (short)(u0>>16), (short)u1, (short)(u1>>16)};
                *(ush4*)(d2 + j) = o;
            }
        }
        return;
    }
    __shared__ unsigned short tile[8][96];
    int r = tid >> 6;                    // wave id = local row
    int row = bid*8 + r;
    int l = tid & 63;
    const float* xr = x + (size_t)row*CC;
    float a = xr[l];
    float b = (l < 32) ? xr[64+l] : 0.0f;
    float s = wave_sum64(a + b);
    float m = s * (1.0f/96.0f);
    float d1f = a - m;
    float d2f = b - m;
    float sq = d1f*d1f + ((l < 32) ? d2f*d2f : 0.0f);
    float var = wave_sum64(sq) * (1.0f/96.0f);
    float rstd = rsqrtf(var + EPSF);
    unsigned short b1 = f2bf(d1f*rstd*w[l] + bb[l]);
    nxbf[(size_t)row*CC + l] = b1;
    tile[r][l] = b1;
    if (l < 32){
        unsigned short b2 = f2bf(d2f*rstd*w[64+l] + bb[64+l]);
        nxbf[(size_t)row*CC + 64 + l] = b2;
        tile[r][64+l] = b2;
    }
    __syncthreads();
    if (tid < 96){
        int row0 = bid*8;
        int bb2 = row0 >> 14, hw = row0 & 16383;
        sh8 v = {(short)tile[0][tid], (short)tile[1][tid], (short)tile[2][tid], (short)tile[3][tid],
                 (short)tile[4][tid], (short)tile[5][tid], (short)tile[6][tid], (short)tile[7][tid]};
        *(sh8*)(nxim + (((size_t)(bb2*96 + tid)) << 14) + hw) = v;
    }
}

// ---------------- conv body (patch GEMM, SPLITK=384 = 6 chunks of 64) ----------------
__device__ __forceinline__ void conv_body(const unsigned short* __restrict__ nxim,
                                          const unsigned short* __restrict__ wbf,
                                          float* __restrict__ part,
                                          int posLog, int pdimLog, int pszLog,
                                          int kTotal, int rb, int split,
                                          unsigned short* pt, unsigned short* wt){
    const int NCH = 6;
    int tid = threadIdx.x;
    int lane = tid & 63, wid = tid >> 6, lo = lane & 15, g = lane >> 4;
    int psz = 1 << pszLog, pdim = 1 << pdimLog;
    int ksLog = 2*pszLog;
    int kb0 = split * 384;
    int cinc = (64 >> ksLog) << 14;

    int j   = tid & 15;
    int coff = (j*4) >> ksLog;
    int s   = (j*4) & (psz*psz - 1);
    int sy  = s >> pszLog, sx = s & (psz-1);
    int pAddr[4], pOff[4];
    #pragma unroll
    for (int i = 0; i < 4; i++){
        int p = (tid >> 4) + 16*i;
        int R = rb*64 + p;
        int b = R >> posLog, pp = R & ((1 << posLog) - 1);
        int pi = pp >> pdimLog, pj = pp & (pdim-1);
        pAddr[i] = (((b*96 + coff) + (kb0 >> ksLog)) << 14) + (pi*psz + sy)*IW + pj*psz + sx;
        pOff[i]  = p*72 + j*4;
    }
    int jj = tid & 7;
    int wAddr[3], wOff[3];
    #pragma unroll
    for (int i = 0; i < 3; i++){
        int o = (tid >> 3) + 32*i;
        wAddr[i] = o*kTotal + kb0 + jj*8;
        wOff[i]  = o*72 + jj*8;
    }

    f32x4 acc[6];
    #pragma unroll
    for (int ct = 0; ct < 6; ct++) acc[ct] = (f32x4){0.f,0.f,0.f,0.f};

    ush4 pr[4]; sh8 wr[3];
    #pragma unroll
    for (int i = 0; i < 4; i++) pr[i] = *(const ush4*)(nxim + pAddr[i]);
    #pragma unroll
    for (int i = 0; i < 3; i++) wr[i] = *(const sh8*)(wbf + wAddr[i]);

    for (int ch = 0; ch < NCH; ch++){
        __syncthreads();
        #pragma unroll
        for (int i = 0; i < 4; i++) *(ush4*)&pt[pOff[i]] = pr[i];
        #pragma unroll
        for (int i = 0; i < 3; i++) *(sh8*)&wt[wOff[i]] = wr[i];
        if (ch < NCH-1){
            #pragma unroll
            for (int i = 0; i < 4; i++){ pAddr[i] += cinc; pr[i] = *(const ush4*)(nxim + pAddr[i]); }
            #pragma unroll
            for (int i = 0; i < 3; i++){ wAddr[i] += 64;  wr[i] = *(const sh8*)(wbf + wAddr[i]); }
        }
        __syncthreads();

        sh8 a0 = *(const sh8*)&pt[(wid*16 + lo)*72 + g*8];
        sh8 a1 = *(const sh8*)&pt[(wid*16 + lo)*72 + 32 + g*8];
        #pragma unroll
        for (int ct = 0; ct < 6; ct++){
            sh8 b0 = *(const sh8*)&wt[(ct*16 + lo)*72 + g*8];
            sh8 b1 = *(const sh8*)&wt[(ct*16 + lo)*72 + 32 + g*8];
            acc[ct] = __builtin_amdgcn_mfma_f32_16x16x32_bf16(a0, b0, acc[ct], 0, 0, 0);
            acc[ct] = __builtin_amdgcn_mfma_f32_16x16x32_bf16(a1, b1, acc[ct], 0, 0, 0);
        }
    }

    int rowsTotal = NB << posLog;
    #pragma unroll
    for (int ct = 0; ct < 6; ct++){
        int o = ct*16 + lo;
        #pragma unroll
        for (int jx = 0; jx < 4; jx++){
            int R = rb*64 + wid*16 + g*4 + jx;
            part[((size_t)split*rowsTotal + R)*96 + o] = acc[ct][jx];
        }
    }
}

// ---------------- 2. merged mid kernel: conv1 ∥ conv2 ∥ hgemm ----------------
__global__ __launch_bounds__(256) void k_mid(const unsigned short* __restrict__ nxbf,
                                             const unsigned short* __restrict__ nxim,
                                             const float* __restrict__ Wh,
                                             const float* __restrict__ bh,
                                             const unsigned short* __restrict__ w1bf,
                                             const unsigned short* __restrict__ w2bf,
                                             unsigned short* __restrict__ vbuf,
                                             unsigned short* __restrict__ gate,
                                             float* __restrict__ part1,
                                             float* __restrict__ part2){
    __shared__ unsigned short smem[192*100];
    int bid = blockIdx.x;
    if (bid < 512){
        unsigned short* pt = smem;
        unsigned short* wt = smem + 64*72;
        if (bid < 256) conv_body(nxim, w1bf, part1, 8, 4, 3, 6144, bid & 15, bid >> 4, pt, wt);
        else { int b2 = bid - 256; conv_body(nxim, w2bf, part2, 10, 5, 2, 1536, b2 & 63, b2 >> 6, pt, wt); }
        return;
    }
    // ---- hgemm ----
    unsigned short* whbf = smem;               // [col][k] stride 100
    int tid  = threadIdx.x;
    int lane = tid & 63;
    int wid  = tid >> 6;
    int lo   = lane & 15;
    int g    = lane >> 4;
    int row0 = (bid - 512)*64 + wid*16;

    #pragma unroll
    for (int it = 0; it < 36; it++){
        int pidx = tid + it*256;
        int k = pidx / 96, cp = (pidx - k*96)*2;
        float2 v = *(const float2*)&Wh[k*HID + cp];
        unsigned u = cvtpk(v.x, v.y);
        whbf[cp*100 + k]     = (unsigned short)u;
        whbf[(cp+1)*100 + k] = (unsigned short)(u >> 16);
    }

    sh8 a[3];
    {
        const unsigned short* ar = nxbf + (size_t)(row0 + lo)*CC;
        #pragma unroll
        for (int kc = 0; kc < 3; kc++)
            a[kc] = *(const sh8*)(ar + kc*32 + g*8);
    }
    __syncthreads();

    f32x4 acc[12];
    #pragma unroll
    for (int ct = 0; ct < 12; ct++) acc[ct] = (f32x4){0.f,0.f,0.f,0.f};
    #pragma unroll
    for (int ct = 0; ct < 12; ct++){
        #pragma unroll
        for (int kc = 0; kc < 3; kc++){
            sh8 bw = *(const sh8*)&whbf[(ct*16 + lo)*100 + kc*32 + g*8];
            acc[ct] = __builtin_amdgcn_mfma_f32_16x16x32_bf16(a[kc], bw, acc[ct], 0, 0, 0);
        }
    }

    #pragma unroll
    for (int ct = 0; ct < 12; ct++){
        int col = ct*16 + lo;
        float bcol = bh[col];
        #pragma unroll
        for (int j = 0; j < 4; j++){
            size_t row = row0 + g*4 + j;
            float hv = siluf(acc[ct][j] + bcol);
            unsigned short hb = (unsigned short)cvtpk(hv, hv);
            if (col < 96) vbuf[row*CC + col] = hb;
            else          gate[row*CC + col - 96] = hb;
        }
    }
}

// ---------------- 4. merged reduce: 4 rows/block, 1 wave per row, no barriers ----------------
__global__ __launch_bounds__(256) void k_reduce(const float* __restrict__ part1,
                                                const float* __restrict__ part2,
                                                const float* __restrict__ cb1, const float* __restrict__ cb2,
                                                const float* __restrict__ lw1, const float* __restrict__ lw2,
                                                const float* __restrict__ lb1, const float* __restrict__ lb2,
                                                const float* __restrict__ wqk,
                                                const float* __restrict__ bqk,
                                                const float* __restrict__ g1, const float* __restrict__ g2,
                                                const float* __restrict__ be1, const float* __restrict__ be2,
                                                unsigned short* __restrict__ qp1, unsigned short* __restrict__ qp2,
                                                unsigned short* __restrict__ kt1, unsigned short* __restrict__ kt2){
    __shared__ float xsh[4][96];
    int wv  = threadIdx.x >> 6;
    int id  = blockIdx.x*4 + wv;         // merged row id (0..5119)
    bool fst = id < 1024;
    int row   = fst ? id : id - 1024;
    int nsplit= fst ? 16 : 4;
    int rows  = fst ? 1024 : 4096;
    int Mper  = fst ? 256 : 1024;
    const float* part = fst ? part1 : part2;
    const float* cbias= fst ? cb1 : cb2;
    const float* lw   = fst ? lw1 : lw2;
    const float* lb   = fst ? lb1 : lb2;
    const float* g    = fst ? g1 : g2;
    const float* be   = fst ? be1 : be2;
    unsigned short* qp = fst ? qp1 : qp2;
    unsigned short* ktp= fst ? kt1 : kt2;

    int l = threadIdx.x & 63;
    float y1 = 0.0f, y2 = 0.0f;
    for (int s = 0; s < nsplit; s++){
        const float* pr = part + ((size_t)s*rows + row)*96;
        y1 += pr[l];
        if (l < 32) y2 += pr[64+l];
    }
    y1 += cbias[l];
    if (l < 32) y2 += cbias[64+l];
    float s = wave_sum64(y1 + ((l < 32) ? y2 : 0.0f));
    float m = s * (1.0f/96.0f);
    float d1 = y1 - m, d2 = y2 - m;
    float var = wave_sum64(d1*d1 + ((l < 32) ? d2*d2 : 0.0f)) * (1.0f/96.0f);
    float rstd = rsqrtf(var + EPSF);
    xsh[wv][l] = geluf(d1*rstd*lw[l] + lb[l]);
    if (l < 32) xsh[wv][64+l] = geluf(d2*rstd*lw[64+l] + lb[64+l]);
    // same-wave LDS write->read: ordered by lgkmcnt, no barrier needed
    if (l < 48){
        float z = bqk[l];
        #pragma unroll 4
        for (int c = 0; c < 96; c++) z += xsh[wv][c]*wqk[c*48 + l];
        z = siluf(z);
        float qv = (z*g[l]    + be[l]) * INV_N;   // fold 1/N into q
        float kv =  z*g[48+l] + be[48+l];
        int b = row / Mper, p = row - b*Mper;
        qp[(size_t)row*64 + l] = f2bf(qv);
        ktp[((size_t)b*48 + l)*Mper + p] = f2bf(kv);
    } else {
        qp[(size_t)row*64 + l] = 0;      // zero the d-pad
    }
}

// ---------------- 5. fused attention(+final): 512 blocks x 128 rows (4 waves x 32, nt=2) ----------------
// Round-22/24 configuration (measured best: q+k LDS-staged, staging amortized over 128 rows).
__global__ __launch_bounds__(256) void k_attn(const unsigned short* __restrict__ vbuf,
                                              const unsigned short* __restrict__ gate,
                                              const unsigned short* __restrict__ qp1,
                                              const unsigned short* __restrict__ ktp1,
                                              const unsigned short* __restrict__ qp2,
                                              const unsigned short* __restrict__ ktp2,
                                              const float* __restrict__ projw,
                                              const float* __restrict__ projb,
                                              float* __restrict__ out){
    __shared__ unsigned short vt1s[4][32*56];   // V1 per wave [32 rows][48 cols] stride 56
    __shared__ unsigned short uni[16896];       // qs dbuf (9216) + ks dbuf (6912) | vt2 (7168) + pjbf (9600)

    int blk  = blockIdx.x;               // 512 blocks x 128 rows
    int tid  = threadIdx.x;
    int wid  = tid >> 6;
    int lane = tid & 63;
    int lo   = lane & 15;
    int g    = lane >> 4;
    int row0 = blk*128 + wid*32;
    int bb   = (blk*128) >> 14;          // batch (uniform per block)

    unsigned short* vt1 = &vt1s[wid][0];
    unsigned short* vt2 = uni + wid*1792;                  // epilogue alias
    unsigned short* pjbf = uni + 7168;                     // epilogue alias [96][100]

    int qm_ = tid >> 3, qc_ = tid & 7;
    int kd_ = tid >> 3, km_ = tid & 7;
    bool k2 = tid < 128;

    for (int kind = 0; kind < 2; kind++){
        int M = kind ? 1024 : 256;
        const unsigned short* qp = (kind ? qp2 : qp1) + (size_t)bb*M*64;
        const unsigned short* kt = (kind ? ktp2 : ktp1) + (size_t)bb*48*M;
        int voff = kind ? 48 : 0;

        sh8 vb[2][2];
        #pragma unroll
        for (int nt = 0; nt < 2; nt++){
            const unsigned short* vrow = vbuf + (size_t)(row0 + nt*16 + lo)*CC + voff;
            vb[nt][0] = *(const sh8*)(vrow + g*8);
            if (g < 2) vb[nt][1] = *(const sh8*)(vrow + 32 + g*8);
            else { sh8 z = {0,0,0,0,0,0,0,0}; vb[nt][1] = z; }
        }

        f32x4 acc[2][3];
        #pragma unroll
        for (int nt = 0; nt < 2; nt++)
            #pragma unroll
            for (int dt = 0; dt < 3; dt++) acc[nt][dt] = (f32x4){0.f,0.f,0.f,0.f};

        int nchunk = M >> 6;
        sh8 qr0 = *(const sh8*)(qp + (size_t)qm_*64 + qc_*8);
        sh8 qr1 = *(const sh8*)(qp + (size_t)(32 + qm_)*64 + qc_*8);
        sh8 kr0 = *(const sh8*)(kt + (size_t)kd_*M + km_*8);
        sh8 kr1;
        if (k2) kr1 = *(const sh8*)(kt + (size_t)(32 + kd_)*M + km_*8);

        for (int ch = 0; ch < nchunk; ch++){
            int bs = ch & 1;
            unsigned short* qb = uni + bs*4608;            // [64*72]
            unsigned short* kb = uni + 9216 + bs*3456;     // [48*72]
            *(sh8*)&qb[qm_*72 + qc_*8] = qr0;
            *(sh8*)&qb[(32 + qm_)*72 + qc_*8] = qr1;
            *(sh8*)&kb[kd_*72 + km_*8] = kr0;
            if (k2) *(sh8*)&kb[(32 + kd_)*72 + km_*8] = kr1;
            __syncthreads();
            if (ch + 1 < nchunk){
                int mb2 = (ch + 1)*64;
                qr0 = *(const sh8*)(qp + (size_t)(mb2 + qm_)*64 + qc_*8);
                qr1 = *(const sh8*)(qp + (size_t)(mb2 + 32 + qm_)*64 + qc_*8);
                kr0 = *(const sh8*)(kt + (size_t)kd_*M + mb2 + km_*8);
                if (k2) kr1 = *(const sh8*)(kt + (size_t)(32 + kd_)*M + mb2 + km_*8);
            }

            f32x4 c[4][2];
            #pragma unroll
            for (int mt = 0; mt < 4; mt++){
                sh8 aq0 = *(const sh8*)&qb[(mt*16 + lo)*72 + g*8];
                sh8 aq1 = *(const sh8*)&qb[(mt*16 + lo)*72 + 32 + g*8];
                #pragma unroll
                for (int nt = 0; nt < 2; nt++){
                    f32x4 cc = (f32x4){0.f,0.f,0.f,0.f};
                    cc = __builtin_amdgcn_mfma_f32_16x16x32_bf16(aq0, vb[nt][0], cc, 0,0,0);
                    cc = __builtin_amdgcn_mfma_f32_16x16x32_bf16(aq1, vb[nt][1], cc, 0,0,0);
                    c[mt][nt] = cc;
                }
            }

            sh8 pa0[2], pa1[2];
            #pragma unroll
            for (int nt = 0; nt < 2; nt++){
                #pragma unroll
                for (int h = 0; h < 2; h++){
                    f32x4 cm0 = c[h*2][nt];
                    f32x4 cm1 = c[h*2+1][nt];
                    float p00 = fmaxf(cm0[0], 0.f); p00 *= p00;
                    float p01 = fmaxf(cm0[1], 0.f); p01 *= p01;
                    float p02 = fmaxf(cm0[2], 0.f); p02 *= p02;
                    float p03 = fmaxf(cm0[3], 0.f); p03 *= p03;
                    float p10 = fmaxf(cm1[0], 0.f); p10 *= p10;
                    float p11 = fmaxf(cm1[1], 0.f); p11 *= p11;
                    float p12 = fmaxf(cm1[2], 0.f); p12 *= p12;
                    float p13 = fmaxf(cm1[3], 0.f); p13 *= p13;
                    unsigned a0 = cvtpk(p00, p01);
                    unsigned a1 = cvtpk(p02, p03);
                    unsigned b0 = cvtpk(p10, p11);
                    unsigned b1 = cvtpk(p12, p13);
                    swap32(a0, b0); swap16(a0, b0);
                    swap32(a1, b1); swap16(a1, b1);
                    union { unsigned u[4]; sh8 v; } pk;
                    pk.u[0] = a0; pk.u[1] = a1; pk.u[2] = b0; pk.u[3] = b1;
                    if (h == 0) pa0[nt] = pk.v; else pa1[nt] = pk.v;
                }
            }

            #pragma unroll
            for (int dt = 0; dt < 3; dt++){
                sh8 bk0 = *(const sh8*)&kb[(dt*16 + lo)*72 + g*8];
                sh8 bk1 = *(const sh8*)&kb[(dt*16 + lo)*72 + 32 + g*8];
                #pragma unroll
                for (int nt = 0; nt < 2; nt++){
                    acc[nt][dt] = __builtin_amdgcn_mfma_f32_16x16x32_bf16(pa0[nt], bk0, acc[nt][dt], 0, 0, 0);
                    acc[nt][dt] = __builtin_amdgcn_mfma_f32_16x16x32_bf16(pa1[nt], bk1, acc[nt][dt], 0, 0, 0);
                }
            }
        }

        if (kind == 0){
            #pragma unroll
            for (int nt = 0; nt < 2; nt++)
                #pragma unroll
                for (int dt = 0; dt < 3; dt++)
                    #pragma unroll
                    for (int j = 0; j < 4; j++)
                        vt1[(nt*16 + g*4 + j)*56 + dt*16 + lo] =
                            (unsigned short)cvtpk(acc[nt][dt][j], acc[nt][dt][j]);
        } else {
            __syncthreads();             // all waves done with qs/ks before vt2/pjbf overwrite
            #pragma unroll
            for (int nt = 0; nt < 2; nt++)
                #pragma unroll
                for (int dt = 0; dt < 3; dt++)
                    #pragma unroll
                    for (int j = 0; j < 4; j++)
                        vt2[(nt*16 + g*4 + j)*56 + dt*16 + lo] =
                            (unsigned short)cvtpk(acc[nt][dt][j], acc[nt][dt][j]);
        }
    }

    #pragma unroll
    for (int it = 0; it < 18; it++){
        int pidx = tid + it*256;
        int k = pidx / 48, cp = (pidx - k*48)*2;
        float2 v = *(const float2*)&projw[k*CC + cp];
        unsigned u = cvtpk(v.x, v.y);
        pjbf[cp*100 + k]     = (unsigned short)u;
        pjbf[(cp+1)*100 + k] = (unsigned short)(u >> 16);
    }
    __syncthreads();

    #pragma unroll
    for (int ntp = 0; ntp < 2; ntp++){
        int rl = ntp*16 + lo;
        size_t grow = row0 + rl;
        sh8 a[3];
        #pragma unroll
        for (int kc = 0; kc < 3; kc++){
            int d0 = kc*32 + g*8;
            const unsigned short* xsrc = (d0 < 48) ? &vt1[rl*56 + d0] : &vt2[rl*56 + d0 - 48];
            union { sh8 v; unsigned u[4]; } xu, gu, pk;
            xu.v = *(const sh8*)xsrc;
            gu.v = *(const sh8*)(gate + grow*CC + d0);
            #pragma unroll
            for (int i = 0; i < 4; i++){
                float xl = b2f(xu.u[i] << 16), xh = b2f(xu.u[i] & 0xffff0000u);
                float gl = b2f(gu.u[i] << 16), gh = b2f(gu.u[i] & 0xffff0000u);
                pk.u[i] = cvtpk(xl*gl, xh*gh);
            }
            a[kc] = pk.v;
        }

        f32x4 pacc[6];
        #pragma unroll
        for (int ct = 0; ct < 6; ct++) pacc[ct] = (f32x4){0.f,0.f,0.f,0.f};
        #pragma unroll
        for (int ct = 0; ct < 6; ct++){
            #pragma unroll
            for (int kc = 0; kc < 3; kc++){
                sh8 bw = *(const sh8*)&pjbf[(ct*16 + lo)*100 + kc*32 + g*8];
                pacc[ct] = __builtin_amdgcn_mfma_f32_16x16x32_bf16(a[kc], bw, pacc[ct], 0, 0, 0);
            }
        }

        #pragma unroll
        for (int ct = 0; ct < 6; ct++){
            int col = ct*16 + lo;
            float bcol = projb[col];
            #pragma unroll
            for (int j = 0; j < 4; j++){
                int rl2 = ntp*16 + g*4 + j;
                unsigned short xb = (col < 48) ? vt1[rl2*56 + col] : vt2[rl2*56 + col - 48];
                out[(size_t)(row0 + rl2)*CC + col] = pacc[ct][j] + bcol + b2f((unsigned)xb << 16);
            }
        }
    }
}

extern "C" void kernel_launch(void* const* d_in, const int* in_sizes, int n_in,
                              void* d_out, int out_size, void* d_ws, size_t ws_size,
                              hipStream_t stream){
    const float* x      = (const float*)d_in[0];
    const float* norm_w = (const float*)d_in[3];
    const float* norm_b = (const float*)d_in[4];
    const float* Wh     = (const float*)d_in[5];
    const float* bh     = (const float*)d_in[6];
    const float* Wqk    = (const float*)d_in[7];
    const float* bqk    = (const float*)d_in[8];
    const float* g1     = (const float*)d_in[9];
    const float* be1    = (const float*)d_in[10];
    const float* g2     = (const float*)d_in[11];
    const float* be2    = (const float*)d_in[12];
    const float* sr1_w  = (const float*)d_in[13];
    const float* sr1_b  = (const float*)d_in[14];
    const float* sr2_w  = (const float*)d_in[15];
    const float* sr2_b  = (const float*)d_in[16];
    const float* n1_w   = (const float*)d_in[17];
    const float* n1_b   = (const float*)d_in[18];
    const float* n2_w   = (const float*)d_in[19];
    const float* n2_b   = (const float*)d_in[20];
    const float* proj_w = (const float*)d_in[21];
    const float* proj_b = (const float*)d_in[22];
    float* out = (float*)d_out;

    float* ws = (float*)d_ws;
    size_t off = 0;
    unsigned short* nxbf = (unsigned short*)(ws + off); off += (size_t)NB*NTOK*CC/2;
    unsigned short* nxim = (unsigned short*)(ws + off); off += (size_t)NB*NTOK*CC/2;
    unsigned short* w1bf = (unsigned short*)(ws + off); off += (size_t)96*6144/2;
    unsigned short* w2bf = (unsigned short*)(ws + off); off += (size_t)96*1536/2;
    unsigned short* vbuf = (unsigned short*)(ws + off); off += (size_t)NB*NTOK*CC/2;
    unsigned short* gate = (unsigned short*)(ws + off); off += (size_t)NB*NTOK*CC/2;
    unsigned short* qp1 = (unsigned short*)(ws + off); off += (size_t)NB*256*64/2;
    unsigned short* kt1 = (unsigned short*)(ws + off); off += (size_t)NB*48*256/2;
    unsigned short* qp2 = (unsigned short*)(ws + off); off += (size_t)NB*1024*64/2;
    unsigned short* kt2 = (unsigned short*)(ws + off); off += (size_t)NB*48*1024/2;
    float* part1= ws + off; off += (size_t)16*NB*256*96;
    float* part2= ws + off; off += (size_t)4*NB*1024*96;
    if (ws_size < off*sizeof(float)) return;

    k_ln   <<<8552, 512, 0, stream>>>(x, norm_w, norm_b, nxbf, nxim,
                                      sr1_w, w1bf, 96*6144, sr2_w, w2bf, 96*1536);
    k_mid  <<<1536, 256, 0, stream>>>(nxbf, nxim, Wh, bh, w1bf, w2bf, vbuf, gate, part1, part2);
    k_reduce<<<1280, 256, 0, stream>>>(part1, part2, sr1_b, sr2_b, n1_w, n2_w, n1_b, n2_b,
                                       Wqk, bqk, g1, g2, be1, be2, qp1, qp2, kt1, kt2);
    k_attn <<<512, 256, 0, stream>>>(vbuf, gate, qp1, kt1, qp2, kt2, proj_w, proj_b, out);
}